// Round 3
// baseline (2071.609 us; speedup 1.0000x reference)
//
#include <hip/hip_runtime.h>
#include <cstddef>
#include <cstdint>

// Problem constants (B=4, S=2048, D=1024, H=16, dh=64)
#define S_LEN  2048
#define DMODEL 1024
#define NHEAD  16
#define DHEAD  64

// 4x4 outer-product accumulate (used by attention kernel)
__device__ __forceinline__ void outer4(float (&acc)[4][4], const float4 a, const float4 b) {
  acc[0][0] += a.x * b.x; acc[0][1] += a.x * b.y; acc[0][2] += a.x * b.z; acc[0][3] += a.x * b.w;
  acc[1][0] += a.y * b.x; acc[1][1] += a.y * b.y; acc[1][2] += a.y * b.z; acc[1][3] += a.y * b.w;
  acc[2][0] += a.z * b.x; acc[2][1] += a.z * b.y; acc[2][2] += a.z * b.z; acc[2][3] += a.z * b.w;
  acc[3][0] += a.w * b.x; acc[3][1] += a.w * b.y; acc[3][2] += a.w * b.z; acc[3][3] += a.w * b.w;
}

// ---------------------------------------------------------------------------
// Kernel 0: RoPE cos/sin tables. table[s*32 + i] for s<2048, pair i<32.
// inv_freq = theta^(-2i/dh), ang = s * inv_freq  (all fp32, matching reference)
// ---------------------------------------------------------------------------
__global__ void rope_table_kernel(float* __restrict__ cosT, float* __restrict__ sinT) {
  const int idx = blockIdx.x * blockDim.x + threadIdx.x;  // 0..65535
  if (idx >= S_LEN * 32) return;
  const int s = idx >> 5;
  const int i = idx & 31;
  const float inv = powf(10000.0f, -(float)(2 * i) / (float)DHEAD);
  const float a = (float)s * inv;
  cosT[idx] = cosf(a);
  sinT[idx] = sinf(a);
}

// ---------------------------------------------------------------------------
// Kernel 1: C = A @ W^T   (A: 8192 x 1024 row-major, W: 1024 x 1024 row-major)
// 128x128 tile, BK=16, 256 threads, 8x8 split micro-tile per thread:
//   rows {ty4+i, 64+ty4+i}, cols {tx4+j, 64+tx4+j}  -> all LDS reads <=2-way
//   or broadcast (free per m136).
// LDS tiles stored transposed [k][row], stride 132.
// mode 0: out[m][n] plain (M x 1024)
// mode 1: RoPE on column pairs, out scattered to (B,H,S,dh)
// mode 2: no RoPE, out scattered to (B,H,S,dh)
// ---------------------------------------------------------------------------
__global__ __launch_bounds__(256) void gemm_nt(const float* __restrict__ A,
                                               const float* __restrict__ W,
                                               float* __restrict__ out,
                                               const float* __restrict__ cosT,
                                               const float* __restrict__ sinT,
                                               int mode) {
  __shared__ float As[16][132];  // [k][row], 16.9KB total for both tiles
  __shared__ float Bs[16][132];
  const int t  = threadIdx.x;
  const int tx = t & 15, ty = t >> 4;
  const int tx4 = tx << 2, ty4 = ty << 2;
  const int mBase = blockIdx.x << 7;
  const int nBase = blockIdx.y << 7;
  // staging: thread t loads rows {srow, 64+srow} at k-offset skq (one float4 each)
  const int srow = t >> 2;          // 0..63
  const int skq  = (t & 3) << 2;    // 0,4,8,12
  const float* Ap0 = A + (size_t)(mBase + srow) * DMODEL + skq;
  const float* Ap1 = Ap0 + (size_t)64 * DMODEL;
  const float* Wp0 = W + (size_t)(nBase + srow) * DMODEL + skq;
  const float* Wp1 = Wp0 + (size_t)64 * DMODEL;

  float acc[8][8] = {};
  for (int kb = 0; kb < DMODEL; kb += 16) {
    const float4 a0 = *(const float4*)(Ap0 + kb);
    const float4 a1 = *(const float4*)(Ap1 + kb);
    const float4 w0 = *(const float4*)(Wp0 + kb);
    const float4 w1 = *(const float4*)(Wp1 + kb);
    __syncthreads();  // previous iteration's compute done before overwrite
    As[skq + 0][srow] = a0.x; As[skq + 1][srow] = a0.y;
    As[skq + 2][srow] = a0.z; As[skq + 3][srow] = a0.w;
    As[skq + 0][64 + srow] = a1.x; As[skq + 1][64 + srow] = a1.y;
    As[skq + 2][64 + srow] = a1.z; As[skq + 3][64 + srow] = a1.w;
    Bs[skq + 0][srow] = w0.x; Bs[skq + 1][srow] = w0.y;
    Bs[skq + 2][srow] = w0.z; Bs[skq + 3][srow] = w0.w;
    Bs[skq + 0][64 + srow] = w1.x; Bs[skq + 1][64 + srow] = w1.y;
    Bs[skq + 2][64 + srow] = w1.z; Bs[skq + 3][64 + srow] = w1.w;
    __syncthreads();
#pragma unroll
    for (int k = 0; k < 16; ++k) {
      const float4 aLo = *(const float4*)&As[k][ty4];
      const float4 aHi = *(const float4*)&As[k][64 + ty4];
      const float4 bLo = *(const float4*)&Bs[k][tx4];
      const float4 bHi = *(const float4*)&Bs[k][64 + tx4];
      const float ar[8] = {aLo.x, aLo.y, aLo.z, aLo.w, aHi.x, aHi.y, aHi.z, aHi.w};
      const float br[8] = {bLo.x, bLo.y, bLo.z, bLo.w, bHi.x, bHi.y, bHi.z, bHi.w};
#pragma unroll
      for (int i = 0; i < 8; ++i)
#pragma unroll
        for (int j = 0; j < 8; ++j)
          acc[i][j] += ar[i] * br[j];
    }
  }

  if (mode == 0) {
#pragma unroll
    for (int ih = 0; ih < 2; ++ih)
#pragma unroll
      for (int i = 0; i < 4; ++i) {
        const int m = mBase + (ih << 6) + ty4 + i;
#pragma unroll
        for (int jh = 0; jh < 2; ++jh) {
          const float4 v = make_float4(acc[ih * 4 + i][jh * 4 + 0], acc[ih * 4 + i][jh * 4 + 1],
                                       acc[ih * 4 + i][jh * 4 + 2], acc[ih * 4 + i][jh * 4 + 3]);
          *(float4*)(out + (size_t)m * DMODEL + nBase + (jh << 6) + tx4) = v;
        }
      }
  } else {
#pragma unroll
    for (int ih = 0; ih < 2; ++ih)
#pragma unroll
      for (int i = 0; i < 4; ++i) {
        const int ai = ih * 4 + i;
        const int m = mBase + (ih << 6) + ty4 + i;
        const int s = m & (S_LEN - 1);
        const int b = m >> 11;
#pragma unroll
        for (int jh = 0; jh < 2; ++jh) {
          const int h = (nBase >> 6) + jh;  // head for this float4 (tx4+3 < 64)
          float e0 = acc[ai][jh * 4 + 0], e1 = acc[ai][jh * 4 + 1];
          float e2 = acc[ai][jh * 4 + 2], e3 = acc[ai][jh * 4 + 3];
          if (mode == 1) {
            const int pi = tx4 >> 1;  // within-head pair index (d = tx4+j)
            const float c0 = cosT[(s << 5) + pi],     s0 = sinT[(s << 5) + pi];
            const float c1 = cosT[(s << 5) + pi + 1], s1 = sinT[(s << 5) + pi + 1];
            const float r0 = e0 * c0 - e1 * s0, r1 = e0 * s0 + e1 * c0;
            const float r2 = e2 * c1 - e3 * s1, r3 = e2 * s1 + e3 * c1;
            e0 = r0; e1 = r1; e2 = r2; e3 = r3;
          }
          const float4 v = make_float4(e0, e1, e2, e3);
          *(float4*)(out + ((size_t)(b * NHEAD + h) * S_LEN + s) * DHEAD + tx4) = v;
        }
      }
  }
}

// ---------------------------------------------------------------------------
// Kernel 2: causal flash attention, fp32.
// Q/K/V in (B,H,S,dh). One block = one (b,h) x 64-query tile. KB=64.
// Output written in (B,S,H*dh) layout (ready for the out-projection GEMM).
// ---------------------------------------------------------------------------
__global__ __launch_bounds__(256) void attn_kernel(const float* __restrict__ Q,
                                                   const float* __restrict__ K,
                                                   const float* __restrict__ V,
                                                   float* __restrict__ O) {
  __shared__ float QsT[64][68];  // [d][qrow]  (transposed)
  __shared__ float KsT[64][68];  // [d][kvrow] (transposed)
  __shared__ float Vs[64][68];   // [kvrow][d] (natural)
  __shared__ float PsT[64][68];  // [kvrow][qrow]
  const int t  = threadIdx.x;
  const int tx = t & 15, ty = t >> 4;
  const int tx4 = tx << 2, ty4 = ty << 2;
  const int bh = blockIdx.y;          // 0..63
  const int q0 = blockIdx.x << 6;
  const size_t bhOff = (size_t)bh * S_LEN * DHEAD;

  // Load Q tile transposed (each rep: wave reads 1KB contiguous)
#pragma unroll
  for (int rep = 0; rep < 4; ++rep) {
    const int fi  = (rep << 8) + t;     // 0..1023
    const int row = fi >> 4;            // 0..63
    const int c4  = (fi & 15) << 2;     // 0..60
    const float4 qv = *(const float4*)(Q + bhOff + (size_t)(q0 + row) * DHEAD + c4);
    QsT[c4 + 0][row] = qv.x; QsT[c4 + 1][row] = qv.y;
    QsT[c4 + 2][row] = qv.z; QsT[c4 + 3][row] = qv.w;
  }

  float m_run[4], l_run[4], o[4][4];
#pragma unroll
  for (int i = 0; i < 4; ++i) {
    m_run[i] = -3.0e38f;
    l_run[i] = 0.0f;
    o[i][0] = o[i][1] = o[i][2] = o[i][3] = 0.0f;
  }

  const int nt = blockIdx.x + 1;  // causal: only tiles up to the diagonal
  for (int tk = 0; tk < nt; ++tk) {
    const int kv0 = tk << 6;
    // prefetch K/V tile into registers (overlaps previous PV compute)
    float4 kpre[4], vpre[4];
#pragma unroll
    for (int rep = 0; rep < 4; ++rep) {
      const int fi  = (rep << 8) + t;
      const int row = fi >> 4;
      const int c4  = (fi & 15) << 2;
      kpre[rep] = *(const float4*)(K + bhOff + (size_t)(kv0 + row) * DHEAD + c4);
      vpre[rep] = *(const float4*)(V + bhOff + (size_t)(kv0 + row) * DHEAD + c4);
    }
    __syncthreads();  // previous iteration fully consumed LDS
#pragma unroll
    for (int rep = 0; rep < 4; ++rep) {
      const int fi  = (rep << 8) + t;
      const int row = fi >> 4;
      const int c4  = (fi & 15) << 2;
      KsT[c4 + 0][row] = kpre[rep].x; KsT[c4 + 1][row] = kpre[rep].y;
      KsT[c4 + 2][row] = kpre[rep].z; KsT[c4 + 3][row] = kpre[rep].w;
      *(float4*)&Vs[row][c4] = vpre[rep];
    }
    __syncthreads();

    // scores: S = Q K^T (64x64), thread owns rows ty4..+3, cols tx4..+3
    float sc4[4][4] = {};
#pragma unroll 16
    for (int k = 0; k < 64; ++k) {
      const float4 a = *(const float4*)&QsT[k][ty4];
      const float4 b = *(const float4*)&KsT[k][tx4];
      outer4(sc4, a, b);
    }

    const bool diag = (tk == (int)blockIdx.x);
#pragma unroll
    for (int i = 0; i < 4; ++i) {
      const int rg = q0 + ty4 + i;
#pragma unroll
      for (int j = 0; j < 4; ++j) {
        float sv = sc4[i][j] * 0.125f;  // 1/sqrt(64)
        if (diag && (kv0 + tx4 + j > rg)) sv = -1.0e9f;  // causal mask (matches ref)
        sc4[i][j] = sv;
      }
      // row max across the 16 lanes sharing this row (consecutive lanes)
      float tm = fmaxf(fmaxf(sc4[i][0], sc4[i][1]), fmaxf(sc4[i][2], sc4[i][3]));
      tm = fmaxf(tm, __shfl_xor(tm, 1));
      tm = fmaxf(tm, __shfl_xor(tm, 2));
      tm = fmaxf(tm, __shfl_xor(tm, 4));
      tm = fmaxf(tm, __shfl_xor(tm, 8));
      const float mn  = fmaxf(m_run[i], tm);
      const float esc = expf(m_run[i] - mn);
      m_run[i] = mn;
      float rs = 0.0f;
#pragma unroll
      for (int j = 0; j < 4; ++j) {
        const float p = expf(sc4[i][j] - mn);
        sc4[i][j] = p;
        rs += p;
      }
      rs += __shfl_xor(rs, 1);
      rs += __shfl_xor(rs, 2);
      rs += __shfl_xor(rs, 4);
      rs += __shfl_xor(rs, 8);
      l_run[i] = l_run[i] * esc + rs;
#pragma unroll
      for (int j = 0; j < 4; ++j) o[i][j] *= esc;
    }

    // stash P transposed for the PV pass
#pragma unroll
    for (int j = 0; j < 4; ++j)
#pragma unroll
      for (int i = 0; i < 4; ++i)
        PsT[tx4 + j][ty4 + i] = sc4[i][j];
    __syncthreads();

    // O += P V : thread owns rows ty4..+3, out-dims tx4..+3
#pragma unroll 16
    for (int c = 0; c < 64; ++c) {
      const float4 p = *(const float4*)&PsT[c][ty4];
      const float4 v = *(const float4*)&Vs[c][tx4];
      outer4(o, p, v);
    }
  }

  // normalize and write to (B, S, H*dh)
  const int b = bh >> 4, h = bh & 15;
#pragma unroll
  for (int i = 0; i < 4; ++i) {
    const int sg = q0 + ty4 + i;
    const float inv = 1.0f / l_run[i];
    float4 v = make_float4(o[i][0] * inv, o[i][1] * inv, o[i][2] * inv, o[i][3] * inv);
    *(float4*)(O + (size_t)(b * S_LEN + sg) * DMODEL + h * DHEAD + tx4) = v;
  }
}

// ---------------------------------------------------------------------------
extern "C" void kernel_launch(void* const* d_in, const int* in_sizes, int n_in,
                              void* d_out, int out_size, void* d_ws, size_t ws_size,
                              hipStream_t stream) {
  const float* x  = (const float*)d_in[0];
  const float* Wq = (const float*)d_in[1];
  const float* Wk = (const float*)d_in[2];
  const float* Wv = (const float*)d_in[3];
  const float* Wo = (const float*)d_in[4];
  // num_heads (d_in[5]) hardcoded as 16

  // workspace layout (floats): Q, K, V (B,H,S,dh), attn (B,S,D), rope tables
  float* ws = (float*)d_ws;
  const size_t MT = (size_t)8192 * DMODEL;  // 8,388,608
  float* Qw   = ws;
  float* Kw   = Qw + MT;
  float* Vw   = Kw + MT;
  float* Aw   = Vw + MT;
  float* cosT = Aw + MT;
  float* sinT = cosT + (size_t)S_LEN * 32;
  // total: 4*MT + 2*65536 floats = ~134.7 MB

  rope_table_kernel<<<256, 256, 0, stream>>>(cosT, sinT);

  dim3 gproj(64, 8);  // M/128, N/128
  gemm_nt<<<gproj, 256, 0, stream>>>(x, Wq, Qw, cosT, sinT, 1);  // Q + RoPE
  gemm_nt<<<gproj, 256, 0, stream>>>(x, Wk, Kw, cosT, sinT, 1);  // K + RoPE
  gemm_nt<<<gproj, 256, 0, stream>>>(x, Wv, Vw, cosT, sinT, 2);  // V

  attn_kernel<<<dim3(32, 64), 256, 0, stream>>>(Qw, Kw, Vw, Aw);

  gemm_nt<<<gproj, 256, 0, stream>>>(Aw, Wo, (float*)d_out, cosT, sinT, 0);  // out-proj
}

// Round 4
// 1034.684 us; speedup vs baseline: 2.0022x; 2.0022x over previous
//
#include <hip/hip_runtime.h>
#include <cstddef>
#include <cstdint>

// Problem constants (B=4, S=2048, D=1024, H=16, dh=64)
#define S_LEN  2048
#define DMODEL 1024
#define NHEAD  16
#define DHEAD  64

typedef __attribute__((ext_vector_type(8))) short short8;  // 8 bf16 (4 VGPRs)
typedef __attribute__((ext_vector_type(4))) float f32x4;   // MFMA acc

// fp32 -> bf16 round-to-nearest-even
__device__ __forceinline__ short f2bf(float f) {
  unsigned u = __float_as_uint(f);
  u += 0x7fffu + ((u >> 16) & 1u);
  return (short)(u >> 16);
}

// 4x4 outer-product accumulate (attention fp32 path)
__device__ __forceinline__ void outer4(float (&acc)[4][4], const float4 a, const float4 b) {
  acc[0][0] += a.x * b.x; acc[0][1] += a.x * b.y; acc[0][2] += a.x * b.z; acc[0][3] += a.x * b.w;
  acc[1][0] += a.y * b.x; acc[1][1] += a.y * b.y; acc[1][2] += a.y * b.z; acc[1][3] += a.y * b.w;
  acc[2][0] += a.z * b.x; acc[2][1] += a.z * b.y; acc[2][2] += a.z * b.z; acc[2][3] += a.z * b.w;
  acc[3][0] += a.w * b.x; acc[3][1] += a.w * b.y; acc[3][2] += a.w * b.z; acc[3][3] += a.w * b.w;
}

// ---------------------------------------------------------------------------
// Kernel 0: RoPE cos/sin tables. table[s*32 + i], fp32 (matches reference).
// ---------------------------------------------------------------------------
__global__ void rope_table_kernel(float* __restrict__ cosT, float* __restrict__ sinT) {
  const int idx = blockIdx.x * blockDim.x + threadIdx.x;  // 0..65535
  if (idx >= S_LEN * 32) return;
  const int s = idx >> 5;
  const int i = idx & 31;
  const float inv = powf(10000.0f, -(float)(2 * i) / (float)DHEAD);
  const float a = (float)s * inv;
  cosT[idx] = cosf(a);
  sinT[idx] = sinf(a);
}

// ---------------------------------------------------------------------------
// Kernel 1: C = A @ W^T via bf16 MFMA (inputs fp32, converted during staging).
// A: M x 1024 row-major, W: 1024 x 1024 row-major (both K-contiguous = the
// verified gemm_bt pattern). 128x128 tile, BK=64, 4 waves in 2x2 grid, each
// wave 64x64 = 4x4 fragments of mfma_f32_16x16x32_bf16.
// LDS tiles [row][64] bf16, XOR-swizzle byte ^= ((row&7)<<4)  (G4 recipe).
// C/D layout (m89/m91 verified): col = lane&15, row = (lane>>4)*4 + reg.
// mode 0: out[m][n] fp32 plain
// mode 1: RoPE on column pairs (via shfl_xor 1), scatter to (B,H,S,dh)
// mode 2: no RoPE, scatter to (B,H,S,dh)
// ---------------------------------------------------------------------------
__global__ __launch_bounds__(256) void gemm_bf16(const float* __restrict__ A,
                                                 const float* __restrict__ W,
                                                 float* __restrict__ out,
                                                 const float* __restrict__ cosT,
                                                 const float* __restrict__ sinT,
                                                 int mode) {
  __shared__ short As[128 * 64];  // 16 KB
  __shared__ short Bs[128 * 64];  // 16 KB
  const int t    = threadIdx.x;
  const int lane = t & 63;
  const int w    = t >> 6;        // wave 0..3
  const int wm   = w >> 1, wn = w & 1;
  const int mBase = blockIdx.x << 7;
  const int nBase = blockIdx.y << 7;
  const int cl = lane & 15;       // fragment col
  const int rg = lane >> 4;       // fragment row group

  f32x4 acc[4][4] = {};

  for (int kb = 0; kb < DMODEL; kb += 64) {
    // load fp32 (global -> regs): quantum qd = t + 256i covers [128 rows][64 k]
    float4 ar[4][2], br[4][2];
#pragma unroll
    for (int i = 0; i < 4; ++i) {
      const int qd  = t + (i << 8);
      const int row = qd >> 3;
      const int k8  = (qd & 7) << 3;
      const float* pa = A + (size_t)(mBase + row) * DMODEL + kb + k8;
      const float* pw = W + (size_t)(nBase + row) * DMODEL + kb + k8;
      ar[i][0] = *(const float4*)pa;
      ar[i][1] = *(const float4*)(pa + 4);
      br[i][0] = *(const float4*)pw;
      br[i][1] = *(const float4*)(pw + 4);
    }
    __syncthreads();  // previous iteration's MFMA reads done
#pragma unroll
    for (int i = 0; i < 4; ++i) {
      const int qd    = t + (i << 8);
      const int row   = qd >> 3;
      const int kbyte = (qd & 7) << 4;
      short8 pa, pw;
      pa[0] = f2bf(ar[i][0].x); pa[1] = f2bf(ar[i][0].y);
      pa[2] = f2bf(ar[i][0].z); pa[3] = f2bf(ar[i][0].w);
      pa[4] = f2bf(ar[i][1].x); pa[5] = f2bf(ar[i][1].y);
      pa[6] = f2bf(ar[i][1].z); pa[7] = f2bf(ar[i][1].w);
      pw[0] = f2bf(br[i][0].x); pw[1] = f2bf(br[i][0].y);
      pw[2] = f2bf(br[i][0].z); pw[3] = f2bf(br[i][0].w);
      pw[4] = f2bf(br[i][1].x); pw[5] = f2bf(br[i][1].y);
      pw[6] = f2bf(br[i][1].z); pw[7] = f2bf(br[i][1].w);
      const int off = ((row << 7) + kbyte) ^ ((row & 7) << 4);
      *(short8*)((char*)As + off) = pa;
      *(short8*)((char*)Bs + off) = pw;
    }
    __syncthreads();
#pragma unroll
    for (int ks = 0; ks < 2; ++ks) {
      const int kof = (ks << 6) + (rg << 4);  // k-slice byte offset
      short8 af[4], bf[4];
#pragma unroll
      for (int mf = 0; mf < 4; ++mf) {
        const int r = (wm << 6) + (mf << 4) + cl;
        af[mf] = *(const short8*)((const char*)As + (((r << 7) + kof) ^ ((r & 7) << 4)));
      }
#pragma unroll
      for (int nf = 0; nf < 4; ++nf) {
        const int r = (wn << 6) + (nf << 4) + cl;
        bf[nf] = *(const short8*)((const char*)Bs + (((r << 7) + kof) ^ ((r & 7) << 4)));
      }
#pragma unroll
      for (int mf = 0; mf < 4; ++mf)
#pragma unroll
        for (int nf = 0; nf < 4; ++nf)
          acc[mf][nf] = __builtin_amdgcn_mfma_f32_16x16x32_bf16(af[mf], bf[nf], acc[mf][nf], 0, 0, 0);
    }
  }

  if (mode == 0) {
#pragma unroll
    for (int mf = 0; mf < 4; ++mf) {
      const int rowb = mBase + (wm << 6) + (mf << 4) + (rg << 2);
#pragma unroll
      for (int nf = 0; nf < 4; ++nf) {
        const int col = nBase + (wn << 6) + (nf << 4) + cl;
#pragma unroll
        for (int r = 0; r < 4; ++r)
          out[(size_t)(rowb + r) * DMODEL + col] = acc[mf][nf][r];
      }
    }
  } else {
    const int h = (nBase >> 6) + wn;  // head for this wave's 64-col block
#pragma unroll
    for (int nf = 0; nf < 4; ++nf) {
      const int d   = (nf << 4) + cl;  // head-dim index 0..63
      const int pi  = d >> 1;
      const bool odd = d & 1;
#pragma unroll
      for (int mf = 0; mf < 4; ++mf) {
#pragma unroll
        for (int r = 0; r < 4; ++r) {
          const int m = mBase + (wm << 6) + (mf << 4) + (rg << 2) + r;
          const int s = m & (S_LEN - 1);
          const int b = m >> 11;
          float v = acc[mf][nf][r];
          if (mode == 1) {
            const float other = __shfl_xor(v, 1);  // partner column d^1
            const float c  = cosT[(s << 5) + pi];
            const float sn = sinT[(s << 5) + pi];
            v = v * c + (odd ? other * sn : -other * sn);
          }
          out[((size_t)(b * NHEAD + h) * S_LEN + s) * DHEAD + d] = v;
        }
      }
    }
  }
}

// ---------------------------------------------------------------------------
// Kernel 2: causal flash attention, fp32, load-balanced.
// Block (p, bh) processes q-tiles {p, 31-p}: (p+1)+(32-p) = 33 kv-iters each.
// Transposed tiles (QsT/KsT/PsT) [row=64][col=64] stride 256B with XOR
// swizzle byte ^= (((row>>2)&7)<<4)  (lanes step rows by 4 -> shift-2 form);
// staged via in-register 4x4 transpose (packed float4 writes, even 8-slot
// bank spread). Vs linear (conflict-free both sides).
// ---------------------------------------------------------------------------
#define TSWZ(row, colbyte) ((((row) << 8) + (colbyte)) ^ ((((row) >> 2) & 7) << 4))

__global__ __launch_bounds__(256) void attn_kernel(const float* __restrict__ Q,
                                                   const float* __restrict__ K,
                                                   const float* __restrict__ V,
                                                   float* __restrict__ O) {
  __shared__ float QsT[64 * 64];  // [d][q]  16 KB
  __shared__ float KsT[64 * 64];  // [d][kv]
  __shared__ float Vs[64 * 64];   // [kv][d]
  __shared__ float PsT[64 * 64];  // [kv][q]
  const int t   = threadIdx.x;
  const int tx  = t & 15, ty = t >> 4;   // 16x16 thread grid
  const int tx4 = tx << 2, ty4 = ty << 2;
  const int bh  = blockIdx.y;
  const int p   = blockIdx.x;            // 0..15
  const size_t bhOff = (size_t)bh * S_LEN * DHEAD;

  for (int pass = 0; pass < 2; ++pass) {
    const int qt = pass ? (31 - p) : p;
    const int q0 = qt << 6;

    // ---- stage Q transposed: thread (tx,ty) loads rows q0+ty4..+3, cols tx4..+3
    {
      float4 r0 = *(const float4*)(Q + bhOff + (size_t)(q0 + ty4 + 0) * DHEAD + tx4);
      float4 r1 = *(const float4*)(Q + bhOff + (size_t)(q0 + ty4 + 1) * DHEAD + tx4);
      float4 r2 = *(const float4*)(Q + bhOff + (size_t)(q0 + ty4 + 2) * DHEAD + tx4);
      float4 r3 = *(const float4*)(Q + bhOff + (size_t)(q0 + ty4 + 3) * DHEAD + tx4);
      *(float4*)((char*)QsT + TSWZ(tx4 + 0, ty << 4)) = make_float4(r0.x, r1.x, r2.x, r3.x);
      *(float4*)((char*)QsT + TSWZ(tx4 + 1, ty << 4)) = make_float4(r0.y, r1.y, r2.y, r3.y);
      *(float4*)((char*)QsT + TSWZ(tx4 + 2, ty << 4)) = make_float4(r0.z, r1.z, r2.z, r3.z);
      *(float4*)((char*)QsT + TSWZ(tx4 + 3, ty << 4)) = make_float4(r0.w, r1.w, r2.w, r3.w);
    }

    float m_run[4], l_run[4], o[4][4];
#pragma unroll
    for (int i = 0; i < 4; ++i) {
      m_run[i] = -3.0e38f;
      l_run[i] = 0.0f;
      o[i][0] = o[i][1] = o[i][2] = o[i][3] = 0.0f;
    }

    for (int tk = 0; tk <= qt; ++tk) {
      const int kv0 = tk << 6;
      // prefetch K/V (overlaps previous PV)
      float4 kr[4], vr[4];
#pragma unroll
      for (int r = 0; r < 4; ++r) {
        kr[r] = *(const float4*)(K + bhOff + (size_t)(kv0 + ty4 + r) * DHEAD + tx4);
        vr[r] = *(const float4*)(V + bhOff + (size_t)(kv0 + ty4 + r) * DHEAD + tx4);
      }
      __syncthreads();  // A: previous iteration fully consumed LDS
      *(float4*)((char*)KsT + TSWZ(tx4 + 0, ty << 4)) = make_float4(kr[0].x, kr[1].x, kr[2].x, kr[3].x);
      *(float4*)((char*)KsT + TSWZ(tx4 + 1, ty << 4)) = make_float4(kr[0].y, kr[1].y, kr[2].y, kr[3].y);
      *(float4*)((char*)KsT + TSWZ(tx4 + 2, ty << 4)) = make_float4(kr[0].z, kr[1].z, kr[2].z, kr[3].z);
      *(float4*)((char*)KsT + TSWZ(tx4 + 3, ty << 4)) = make_float4(kr[0].w, kr[1].w, kr[2].w, kr[3].w);
#pragma unroll
      for (int r = 0; r < 4; ++r)
        *(float4*)(Vs + (size_t)(ty4 + r) * 64 + tx4) = vr[r];
      __syncthreads();  // B: tiles ready

      // scores S = Q K^T: thread owns q-rows ty4..+3, kv-cols tx4..+3
      float sc4[4][4] = {};
#pragma unroll 16
      for (int k = 0; k < 64; ++k) {
        const float4 a = *(const float4*)((const char*)QsT + TSWZ(k, ty << 4));
        const float4 b = *(const float4*)((const char*)KsT + TSWZ(k, tx << 4));
        outer4(sc4, a, b);
      }

      const bool diag = (tk == qt);
#pragma unroll
      for (int i = 0; i < 4; ++i) {
        const int rgq = q0 + ty4 + i;
#pragma unroll
        for (int j = 0; j < 4; ++j) {
          float sv = sc4[i][j] * 0.125f;  // 1/sqrt(64)
          if (diag && (kv0 + tx4 + j > rgq)) sv = -1.0e9f;
          sc4[i][j] = sv;
        }
        float tm = fmaxf(fmaxf(sc4[i][0], sc4[i][1]), fmaxf(sc4[i][2], sc4[i][3]));
        tm = fmaxf(tm, __shfl_xor(tm, 1));
        tm = fmaxf(tm, __shfl_xor(tm, 2));
        tm = fmaxf(tm, __shfl_xor(tm, 4));
        tm = fmaxf(tm, __shfl_xor(tm, 8));
        const float mn  = fmaxf(m_run[i], tm);
        const float esc = expf(m_run[i] - mn);
        m_run[i] = mn;
        float rs = 0.0f;
#pragma unroll
        for (int j = 0; j < 4; ++j) {
          const float pv = expf(sc4[i][j] - mn);
          sc4[i][j] = pv;
          rs += pv;
        }
        rs += __shfl_xor(rs, 1);
        rs += __shfl_xor(rs, 2);
        rs += __shfl_xor(rs, 4);
        rs += __shfl_xor(rs, 8);
        l_run[i] = l_run[i] * esc + rs;
#pragma unroll
        for (int j = 0; j < 4; ++j) o[i][j] *= esc;
      }

      // P^T stash: PsT[kv = tx4+j][q = ty4..+3], packed float4 over i
#pragma unroll
      for (int j = 0; j < 4; ++j)
        *(float4*)((char*)PsT + TSWZ(tx4 + j, ty << 4)) =
            make_float4(sc4[0][j], sc4[1][j], sc4[2][j], sc4[3][j]);
      __syncthreads();  // C

      // O += P V
#pragma unroll 16
      for (int c = 0; c < 64; ++c) {
        const float4 p4 = *(const float4*)((const char*)PsT + TSWZ(c, ty << 4));
        const float4 v4 = *(const float4*)(Vs + (size_t)c * 64 + tx4);
        outer4(o, p4, v4);
      }
    }

    // normalize, write to (B,S,H*dh)
    const int b = bh >> 4, h = bh & 15;
#pragma unroll
    for (int i = 0; i < 4; ++i) {
      const int sg = q0 + ty4 + i;
      const float inv = 1.0f / l_run[i];
      float4 v = make_float4(o[i][0] * inv, o[i][1] * inv, o[i][2] * inv, o[i][3] * inv);
      *(float4*)(O + (size_t)(b * S_LEN + sg) * DMODEL + h * DHEAD + tx4) = v;
    }
  }
}

// ---------------------------------------------------------------------------
extern "C" void kernel_launch(void* const* d_in, const int* in_sizes, int n_in,
                              void* d_out, int out_size, void* d_ws, size_t ws_size,
                              hipStream_t stream) {
  const float* x  = (const float*)d_in[0];
  const float* Wq = (const float*)d_in[1];
  const float* Wk = (const float*)d_in[2];
  const float* Wv = (const float*)d_in[3];
  const float* Wo = (const float*)d_in[4];
  // num_heads (d_in[5]) hardcoded as 16

  float* ws = (float*)d_ws;
  const size_t MT = (size_t)8192 * DMODEL;
  float* Qw   = ws;
  float* Kw   = Qw + MT;
  float* Vw   = Kw + MT;
  float* Aw   = Vw + MT;
  float* cosT = Aw + MT;
  float* sinT = cosT + (size_t)S_LEN * 32;  // total ~134.7 MB

  rope_table_kernel<<<256, 256, 0, stream>>>(cosT, sinT);

  dim3 gproj(64, 8);  // M/128, N/128
  gemm_bf16<<<gproj, 256, 0, stream>>>(x, Wq, Qw, cosT, sinT, 1);  // Q + RoPE
  gemm_bf16<<<gproj, 256, 0, stream>>>(x, Wk, Kw, cosT, sinT, 1);  // K + RoPE
  gemm_bf16<<<gproj, 256, 0, stream>>>(x, Wv, Vw, cosT, sinT, 2);  // V

  attn_kernel<<<dim3(16, 64), 256, 0, stream>>>(Qw, Kw, Vw, Aw);

  gemm_bf16<<<gproj, 256, 0, stream>>>(Aw, Wo, (float*)d_out, cosT, sinT, 0);  // out-proj
}

// Round 5
// 660.906 us; speedup vs baseline: 3.1345x; 1.5656x over previous
//
#include <hip/hip_runtime.h>
#include <cstddef>
#include <cstdint>

// Problem constants (B=4, S=2048, D=1024, H=16, dh=64)
#define S_LEN  2048
#define DMODEL 1024
#define NHEAD  16
#define DHEAD  64

typedef __attribute__((ext_vector_type(8))) short bf16x8;  // 8 bf16 (4 VGPRs)
typedef __attribute__((ext_vector_type(4))) short bf16x4;  // 4 bf16 (8B)
typedef __attribute__((ext_vector_type(4))) float f32x4;   // MFMA acc

// fp32 -> bf16 round-to-nearest-even
__device__ __forceinline__ short f2bf(float f) {
  unsigned u = __float_as_uint(f);
  u += 0x7fffu + ((u >> 16) & 1u);
  return (short)(u >> 16);
}

// bf16 LDS tile [row][64], row = 128B, XOR swizzle (G4): spreads the 8 16B
// slots of a row across banks; lanes reading 16 different rows at one slot
// land 2-way (free).
#define SW(row, byteInRow) ((((row) << 7) + (byteInRow)) ^ (((row) & 7) << 4))

// ---------------------------------------------------------------------------
// Kernel 0: RoPE cos/sin tables. table[s*32 + i], fp32 (matches reference).
// ---------------------------------------------------------------------------
__global__ void rope_table_kernel(float* __restrict__ cosT, float* __restrict__ sinT) {
  const int idx = blockIdx.x * blockDim.x + threadIdx.x;  // 0..65535
  if (idx >= S_LEN * 32) return;
  const int s = idx >> 5;
  const int i = idx & 31;
  const float inv = powf(10000.0f, -(float)(2 * i) / (float)DHEAD);
  const float a = (float)s * inv;
  cosT[idx] = cosf(a);
  sinT[idx] = sinf(a);
}

// ---------------------------------------------------------------------------
// Kernel 1: C = A @ W^T via bf16 MFMA. 128x128 tile, BK=64, 4 waves 2x2.
// (Layout triple verified on HW by round-4 PASS: A row=lane&15 k-contig,
//  B^T row-major k-contig, C/D col=lane&15 row=(lane>>4)*4+reg.)
// mode 0: fp32 out[m][n]
// mode 1: RoPE, bf16 out [bh][s][64]        (Q and K)
// mode 2: bf16 out transposed [bh][d][s]    (V -> VT)
// ---------------------------------------------------------------------------
__global__ __launch_bounds__(256) void gemm_bf16(const float* __restrict__ A,
                                                 const float* __restrict__ W,
                                                 void* __restrict__ outv,
                                                 const float* __restrict__ cosT,
                                                 const float* __restrict__ sinT,
                                                 int mode) {
  __shared__ short As[128 * 64];  // 16 KB
  __shared__ short Bs[128 * 64];  // 16 KB
  const int t    = threadIdx.x;
  const int lane = t & 63;
  const int w    = t >> 6;        // wave 0..3
  const int wm   = w >> 1, wn = w & 1;
  const int mBase = blockIdx.x << 7;
  const int nBase = blockIdx.y << 7;
  const int cl = lane & 15;       // fragment col
  const int rg = lane >> 4;       // fragment row group

  f32x4 acc[4][4] = {};

  for (int kb = 0; kb < DMODEL; kb += 64) {
    float4 ar[4][2], br[4][2];
#pragma unroll
    for (int i = 0; i < 4; ++i) {
      const int qd  = t + (i << 8);
      const int row = qd >> 3;
      const int k8  = (qd & 7) << 3;
      const float* pa = A + (size_t)(mBase + row) * DMODEL + kb + k8;
      const float* pw = W + (size_t)(nBase + row) * DMODEL + kb + k8;
      ar[i][0] = *(const float4*)pa;
      ar[i][1] = *(const float4*)(pa + 4);
      br[i][0] = *(const float4*)pw;
      br[i][1] = *(const float4*)(pw + 4);
    }
    __syncthreads();
#pragma unroll
    for (int i = 0; i < 4; ++i) {
      const int qd    = t + (i << 8);
      const int row   = qd >> 3;
      const int kbyte = (qd & 7) << 4;
      bf16x8 pa, pw;
      pa[0] = f2bf(ar[i][0].x); pa[1] = f2bf(ar[i][0].y);
      pa[2] = f2bf(ar[i][0].z); pa[3] = f2bf(ar[i][0].w);
      pa[4] = f2bf(ar[i][1].x); pa[5] = f2bf(ar[i][1].y);
      pa[6] = f2bf(ar[i][1].z); pa[7] = f2bf(ar[i][1].w);
      pw[0] = f2bf(br[i][0].x); pw[1] = f2bf(br[i][0].y);
      pw[2] = f2bf(br[i][0].z); pw[3] = f2bf(br[i][0].w);
      pw[4] = f2bf(br[i][1].x); pw[5] = f2bf(br[i][1].y);
      pw[6] = f2bf(br[i][1].z); pw[7] = f2bf(br[i][1].w);
      const int off = ((row << 7) + kbyte) ^ ((row & 7) << 4);
      *(bf16x8*)((char*)As + off) = pa;
      *(bf16x8*)((char*)Bs + off) = pw;
    }
    __syncthreads();
#pragma unroll
    for (int ks = 0; ks < 2; ++ks) {
      const int kof = (ks << 6) + (rg << 4);
      bf16x8 af[4], bfr[4];
#pragma unroll
      for (int mf = 0; mf < 4; ++mf) {
        const int r = (wm << 6) + (mf << 4) + cl;
        af[mf] = *(const bf16x8*)((const char*)As + (((r << 7) + kof) ^ ((r & 7) << 4)));
      }
#pragma unroll
      for (int nf = 0; nf < 4; ++nf) {
        const int r = (wn << 6) + (nf << 4) + cl;
        bfr[nf] = *(const bf16x8*)((const char*)Bs + (((r << 7) + kof) ^ ((r & 7) << 4)));
      }
#pragma unroll
      for (int mf = 0; mf < 4; ++mf)
#pragma unroll
        for (int nf = 0; nf < 4; ++nf)
          acc[mf][nf] = __builtin_amdgcn_mfma_f32_16x16x32_bf16(af[mf], bfr[nf], acc[mf][nf], 0, 0, 0);
    }
  }

  if (mode == 0) {
    float* out = (float*)outv;
#pragma unroll
    for (int mf = 0; mf < 4; ++mf) {
      const int rowb = mBase + (wm << 6) + (mf << 4) + (rg << 2);
#pragma unroll
      for (int nf = 0; nf < 4; ++nf) {
        const int col = nBase + (wn << 6) + (nf << 4) + cl;
#pragma unroll
        for (int r = 0; r < 4; ++r)
          out[(size_t)(rowb + r) * DMODEL + col] = acc[mf][nf][r];
      }
    }
  } else if (mode == 1) {
    // RoPE + bf16 scatter to [bh][s][64]
    unsigned short* out = (unsigned short*)outv;
    const int h = (nBase >> 6) + wn;
#pragma unroll
    for (int nf = 0; nf < 4; ++nf) {
      const int d   = (nf << 4) + cl;  // 0..63
      const int pi  = d >> 1;
      const bool odd = d & 1;
#pragma unroll
      for (int mf = 0; mf < 4; ++mf) {
#pragma unroll
        for (int r = 0; r < 4; ++r) {
          const int m = mBase + (wm << 6) + (mf << 4) + (rg << 2) + r;
          const int s = m & (S_LEN - 1);
          const int b = m >> 11;
          float v = acc[mf][nf][r];
          const float other = __shfl_xor(v, 1);  // partner column d^1
          const float c  = cosT[(s << 5) + pi];
          const float sn = sinT[(s << 5) + pi];
          v = v * c + (odd ? other * sn : -other * sn);
          out[((size_t)(b * NHEAD + h) * S_LEN + s) * DHEAD + d] = (unsigned short)f2bf(v);
        }
      }
    }
  } else {
    // V: bf16 transposed scatter to VT [bh][d][s]
    unsigned short* out = (unsigned short*)outv;
    const int h = (nBase >> 6) + wn;
#pragma unroll
    for (int mf = 0; mf < 4; ++mf) {
      const int m0 = mBase + (wm << 6) + (mf << 4) + (rg << 2);
      const int s0 = m0 & (S_LEN - 1);   // 4-aligned, contiguous over r
      const int b  = m0 >> 11;
#pragma unroll
      for (int nf = 0; nf < 4; ++nf) {
        const int d = (nf << 4) + cl;
        bf16x4 pk;
        pk[0] = f2bf(acc[mf][nf][0]); pk[1] = f2bf(acc[mf][nf][1]);
        pk[2] = f2bf(acc[mf][nf][2]); pk[3] = f2bf(acc[mf][nf][3]);
        *(bf16x4*)(out + ((size_t)(b * NHEAD + h) * DHEAD + d) * S_LEN + s0) = pk;
      }
    }
  }
}

// ---------------------------------------------------------------------------
// Kernel 2: causal flash attention, bf16 MFMA.
// Grid (16, 64); block (p,bh) does q-tiles {p, 31-p} (33 kv-iters, balanced).
// 4 waves; wave w owns q-rows [w*16, w*16+16) of the 64-row tile.
// LDS (bf16, 8KB each, XOR-swizzled): Qs[q][d], Ks[kv][d], Vs[d][kv], Ps[q][kv].
// QK^T: A=Q,B=K (k=d). PV: A=P,B=VT (k=kv). P round-trips through
// wave-private LDS rows (no barrier, explicit lgkmcnt).
// Output fp32 (B,S,H*dh).
// ---------------------------------------------------------------------------
__global__ __launch_bounds__(256) void attn_mfma(const unsigned short* __restrict__ Qbf,
                                                 const unsigned short* __restrict__ Kbf,
                                                 const unsigned short* __restrict__ VTbf,
                                                 float* __restrict__ O) {
  __shared__ short Qs[64 * 64];
  __shared__ short Ks[64 * 64];
  __shared__ short Vs[64 * 64];
  __shared__ short Ps[64 * 64];
  const int t    = threadIdx.x;
  const int lane = t & 63;
  const int w    = t >> 6;
  const int cl   = lane & 15;
  const int rg   = lane >> 4;
  const int qw   = w << 4;            // wave's q-row base within tile
  const int bh   = blockIdx.y;
  const int p    = blockIdx.x;        // 0..15
  const int b    = bh >> 4, h = bh & 15;

  const unsigned short* kbase = Kbf + (size_t)bh * S_LEN * DHEAD;
  const unsigned short* vbase = VTbf + (size_t)bh * DHEAD * S_LEN;

  // block-wide staging map for K/VT tiles (64 rows x 128B)
  const int srow  = t >> 2;
  const int sslot = t & 3;

  for (int pass = 0; pass < 2; ++pass) {
    const int qt = pass ? (31 - p) : p;
    const int q0 = qt << 6;

    // ---- stage Q (wave-private rows qw..qw+15)
    {
      const int qrow = qw + (lane >> 2);
      const int qsl  = lane & 3;
      const unsigned short* qp =
          Qbf + ((size_t)bh * S_LEN + q0 + qrow) * DHEAD + (qsl << 4);
      const bf16x8 qa = *(const bf16x8*)qp;
      const bf16x8 qb = *(const bf16x8*)(qp + 8);
      asm volatile("s_waitcnt lgkmcnt(0)" ::: "memory");  // prev-pass LDS reads done
      *(bf16x8*)((char*)Qs + SW(qrow, (qsl << 5)))      = qa;
      *(bf16x8*)((char*)Qs + SW(qrow, (qsl << 5) + 16)) = qb;
    }

    f32x4 oacc[4];
#pragma unroll
    for (int nf = 0; nf < 4; ++nf) oacc[nf] = (f32x4){0.f, 0.f, 0.f, 0.f};
    float m_run[4], l_run[4];
#pragma unroll
    for (int r = 0; r < 4; ++r) { m_run[r] = -3.0e38f; l_run[r] = 0.0f; }

    for (int tk = 0; tk <= qt; ++tk) {
      const int kv0 = tk << 6;
      // prefetch K / VT tile slices (global, bf16)
      const unsigned short* kp = kbase + (size_t)(kv0 + srow) * DHEAD + (sslot << 4);
      const unsigned short* vp = vbase + (size_t)srow * S_LEN + kv0 + (sslot << 4);
      const bf16x8 k0 = *(const bf16x8*)kp;
      const bf16x8 k1 = *(const bf16x8*)(kp + 8);
      const bf16x8 v0 = *(const bf16x8*)vp;
      const bf16x8 v1 = *(const bf16x8*)(vp + 8);
      __syncthreads();  // A: previous tile's LDS reads complete
      *(bf16x8*)((char*)Ks + SW(srow, (sslot << 5)))      = k0;
      *(bf16x8*)((char*)Ks + SW(srow, (sslot << 5) + 16)) = k1;
      *(bf16x8*)((char*)Vs + SW(srow, (sslot << 5)))      = v0;
      *(bf16x8*)((char*)Vs + SW(srow, (sslot << 5) + 16)) = v1;
      __syncthreads();  // B: tiles ready

      // ---- QK^T: wave computes 16 q-rows x 64 kv
      f32x4 sfrag[4];
#pragma unroll
      for (int nf = 0; nf < 4; ++nf) sfrag[nf] = (f32x4){0.f, 0.f, 0.f, 0.f};
#pragma unroll
      for (int ks = 0; ks < 2; ++ks) {
        const bf16x8 aq = *(const bf16x8*)((const char*)Qs + SW(qw + cl, (ks << 6) + (rg << 4)));
#pragma unroll
        for (int nf = 0; nf < 4; ++nf) {
          const bf16x8 bk = *(const bf16x8*)((const char*)Ks + SW((nf << 4) + cl, (ks << 6) + (rg << 4)));
          sfrag[nf] = __builtin_amdgcn_mfma_f32_16x16x32_bf16(aq, bk, sfrag[nf], 0, 0, 0);
        }
      }

      // ---- online softmax (row q = qw + rg*4 + r, lane-local over cl/nf)
      const bool diag = (tk == qt);
      float esc4[4];
#pragma unroll
      for (int r = 0; r < 4; ++r) {
        const int qg = q0 + qw + (rg << 2) + r;
        float sv[4];
#pragma unroll
        for (int nf = 0; nf < 4; ++nf) {
          float x = sfrag[nf][r] * 0.125f;  // 1/sqrt(64)
          if (diag && (kv0 + (nf << 4) + cl > qg)) x = -1.0e9f;
          sv[nf] = x;
        }
        float tm = fmaxf(fmaxf(sv[0], sv[1]), fmaxf(sv[2], sv[3]));
        tm = fmaxf(tm, __shfl_xor(tm, 1));
        tm = fmaxf(tm, __shfl_xor(tm, 2));
        tm = fmaxf(tm, __shfl_xor(tm, 4));
        tm = fmaxf(tm, __shfl_xor(tm, 8));
        const float mn  = fmaxf(m_run[r], tm);
        const float esc = __expf(m_run[r] - mn);
        m_run[r] = mn;
        float rs = 0.0f;
        unsigned short pb[4];
#pragma unroll
        for (int nf = 0; nf < 4; ++nf) {
          const float pv = __expf(sv[nf] - mn);
          rs += pv;
          pb[nf] = (unsigned short)f2bf(pv);
        }
        rs += __shfl_xor(rs, 1);
        rs += __shfl_xor(rs, 2);
        rs += __shfl_xor(rs, 4);
        rs += __shfl_xor(rs, 8);
        l_run[r] = l_run[r] * esc + rs;
        esc4[r] = esc;
        const int prow = qw + (rg << 2) + r;  // wave-private P row
#pragma unroll
        for (int nf = 0; nf < 4; ++nf)
          *(unsigned short*)((char*)Ps + SW(prow, (nf << 5) + (cl << 1))) = pb[nf];
      }

      // rescale O accumulator (lane-local: oacc row r has same q as esc4[r])
#pragma unroll
      for (int nf = 0; nf < 4; ++nf)
#pragma unroll
        for (int r = 0; r < 4; ++r) oacc[nf][r] *= esc4[r];

      asm volatile("s_waitcnt lgkmcnt(0)" ::: "memory");  // P writes visible (same wave)

      // ---- PV: O[16 q][64 d] += P[16 q][64 kv] * VT^T
#pragma unroll
      for (int ks = 0; ks < 2; ++ks) {
        const bf16x8 ap = *(const bf16x8*)((const char*)Ps + SW(qw + cl, (ks << 6) + (rg << 4)));
#pragma unroll
        for (int nf = 0; nf < 4; ++nf) {
          const bf16x8 bv = *(const bf16x8*)((const char*)Vs + SW((nf << 4) + cl, (ks << 6) + (rg << 4)));
          oacc[nf] = __builtin_amdgcn_mfma_f32_16x16x32_bf16(ap, bv, oacc[nf], 0, 0, 0);
        }
      }
    }

    // ---- epilogue: normalize, write fp32 (B,S,H*dh)
#pragma unroll
    for (int r = 0; r < 4; ++r) {
      const float inv = 1.0f / l_run[r];
      const int sg = q0 + qw + (rg << 2) + r;
      float* orow = O + ((size_t)b * S_LEN + sg) * DMODEL + h * DHEAD;
#pragma unroll
      for (int nf = 0; nf < 4; ++nf)
        orow[(nf << 4) + cl] = oacc[nf][r] * inv;
    }
  }
}

// ---------------------------------------------------------------------------
extern "C" void kernel_launch(void* const* d_in, const int* in_sizes, int n_in,
                              void* d_out, int out_size, void* d_ws, size_t ws_size,
                              hipStream_t stream) {
  const float* x  = (const float*)d_in[0];
  const float* Wq = (const float*)d_in[1];
  const float* Wk = (const float*)d_in[2];
  const float* Wv = (const float*)d_in[3];
  const float* Wo = (const float*)d_in[4];
  // num_heads (d_in[5]) hardcoded as 16

  // workspace: Aw fp32 (33.6MB) | Qbf | Kbf | VTbf (16.8MB each) | tables
  float* Aw = (float*)d_ws;
  unsigned short* Qbf  = (unsigned short*)((char*)d_ws + (size_t)33554432);
  unsigned short* Kbf  = Qbf + (size_t)8388608;
  unsigned short* VTbf = Kbf + (size_t)8388608;
  float* cosT = (float*)(VTbf + (size_t)8388608);
  float* sinT = cosT + 65536;  // total ~84.4 MB

  rope_table_kernel<<<256, 256, 0, stream>>>(cosT, sinT);

  dim3 gproj(64, 8);  // M/128, N/128
  gemm_bf16<<<gproj, 256, 0, stream>>>(x, Wq, Qbf,  cosT, sinT, 1);  // Q + RoPE -> bf16
  gemm_bf16<<<gproj, 256, 0, stream>>>(x, Wk, Kbf,  cosT, sinT, 1);  // K + RoPE -> bf16
  gemm_bf16<<<gproj, 256, 0, stream>>>(x, Wv, VTbf, cosT, sinT, 2);  // V -> VT bf16

  attn_mfma<<<dim3(16, 64), 256, 0, stream>>>(Qbf, Kbf, VTbf, Aw);

  gemm_bf16<<<gproj, 256, 0, stream>>>(Aw, Wo, d_out, cosT, sinT, 0);  // out-proj fp32
}

// Round 6
// 314.175 us; speedup vs baseline: 6.5938x; 2.1036x over previous
//
#include <hip/hip_runtime.h>
#include <cstddef>
#include <cstdint>

// Problem constants (B=4, S=2048, D=1024, H=16, dh=64)
#define S_LEN  2048
#define DMODEL 1024
#define NHEAD  16
#define DHEAD  64

typedef __attribute__((ext_vector_type(8))) short bf16x8;  // 8 bf16 (4 VGPRs)
typedef __attribute__((ext_vector_type(4))) float f32x4;   // MFMA acc

// fp32 -> bf16 round-to-nearest-even
__device__ __forceinline__ short f2bf(float f) {
  unsigned u = __float_as_uint(f);
  u += 0x7fffu + ((u >> 16) & 1u);
  return (short)(u >> 16);
}

// bf16 LDS tile [row][64], row = 128B, XOR swizzle (G4, HW-verified r4/r5)
#define SW(row, byteInRow) ((((row) << 7) + (byteInRow)) ^ (((row) & 7) << 4))

// ---------------------------------------------------------------------------
// Kernel 0: RoPE cos/sin tables. table[s*32 + i], fp32 (matches reference).
// ---------------------------------------------------------------------------
__global__ void rope_table_kernel(float* __restrict__ cosT, float* __restrict__ sinT) {
  const int idx = blockIdx.x * blockDim.x + threadIdx.x;  // 0..65535
  if (idx >= S_LEN * 32) return;
  const int s = idx >> 5;
  const int i = idx & 31;
  const float inv = powf(10000.0f, -(float)(2 * i) / (float)DHEAD);
  const float a = (float)s * inv;
  cosT[idx] = cosf(a);
  sinT[idx] = sinf(a);
}

// ---------------------------------------------------------------------------
// Kernel 0b: fp32 -> bf16 bulk convert: x (4096 blk), Wq/Wk/Wv/Wo (512 each).
// 2048 elements per block (8/thread), vectorized.
// ---------------------------------------------------------------------------
__global__ __launch_bounds__(256) void convert_kernel(
    const float* __restrict__ x,  const float* __restrict__ wq,
    const float* __restrict__ wk, const float* __restrict__ wv,
    const float* __restrict__ wo,
    unsigned short* __restrict__ xb,  unsigned short* __restrict__ wqb,
    unsigned short* __restrict__ wkb, unsigned short* __restrict__ wvb,
    unsigned short* __restrict__ wob) {
  const int blk = blockIdx.x;
  const float* src;
  unsigned short* dst;
  size_t base;
  if (blk < 4096)      { src = x;  dst = xb;  base = (size_t)blk * 2048; }
  else if (blk < 4608) { src = wq; dst = wqb; base = (size_t)(blk - 4096) * 2048; }
  else if (blk < 5120) { src = wk; dst = wkb; base = (size_t)(blk - 4608) * 2048; }
  else if (blk < 5632) { src = wv; dst = wvb; base = (size_t)(blk - 5120) * 2048; }
  else                 { src = wo; dst = wob; base = (size_t)(blk - 5632) * 2048; }
  const size_t o = base + (size_t)threadIdx.x * 8;
  const float4 v0 = *(const float4*)(src + o);
  const float4 v1 = *(const float4*)(src + o + 4);
  bf16x8 p;
  p[0] = f2bf(v0.x); p[1] = f2bf(v0.y); p[2] = f2bf(v0.z); p[3] = f2bf(v0.w);
  p[4] = f2bf(v1.x); p[5] = f2bf(v1.y); p[6] = f2bf(v1.z); p[7] = f2bf(v1.w);
  *(bf16x8*)(dst + o) = p;
}

// ---------------------------------------------------------------------------
// GEMM core (bf16 inputs): 128x128 tile, BK=64, 4 waves 2x2, 4x4 fragments of
// mfma_f32_16x16x32_bf16. Layout triple HW-verified (r4/r5 PASS).
// Staging: 4x bf16x8 per operand per thread (128B), zero conversions.
// ---------------------------------------------------------------------------
#define GEMM_CORE(A_, W_, mBase_, nBase_)                                          \
  f32x4 acc[4][4] = {};                                                            \
  for (int kb = 0; kb < DMODEL; kb += 64) {                                        \
    bf16x8 ar[4], br[4];                                                           \
    _Pragma("unroll")                                                              \
    for (int i = 0; i < 4; ++i) {                                                  \
      const int qd  = t + (i << 8);                                                \
      const int row = qd >> 3;                                                     \
      const int sl  = qd & 7;                                                      \
      ar[i] = *(const bf16x8*)(A_ + (size_t)(mBase_ + row) * DMODEL + kb + (sl << 3)); \
      br[i] = *(const bf16x8*)(W_ + (size_t)(nBase_ + row) * DMODEL + kb + (sl << 3)); \
    }                                                                              \
    __syncthreads();                                                               \
    _Pragma("unroll")                                                              \
    for (int i = 0; i < 4; ++i) {                                                  \
      const int qd  = t + (i << 8);                                                \
      const int row = qd >> 3;                                                     \
      const int sl  = qd & 7;                                                      \
      const int off = ((row << 7) + (sl << 4)) ^ ((row & 7) << 4);                 \
      *(bf16x8*)((char*)As + off) = ar[i];                                         \
      *(bf16x8*)((char*)Bs + off) = br[i];                                         \
    }                                                                              \
    __syncthreads();                                                               \
    _Pragma("unroll")                                                              \
    for (int ks = 0; ks < 2; ++ks) {                                               \
      const int kof = (ks << 6) + (rg << 4);                                       \
      bf16x8 af[4], bfr[4];                                                        \
      _Pragma("unroll")                                                            \
      for (int mf = 0; mf < 4; ++mf) {                                             \
        const int r = (wm << 6) + (mf << 4) + cl;                                  \
        af[mf] = *(const bf16x8*)((const char*)As + (((r << 7) + kof) ^ ((r & 7) << 4))); \
      }                                                                            \
      _Pragma("unroll")                                                            \
      for (int nf = 0; nf < 4; ++nf) {                                             \
        const int r = (wn << 6) + (nf << 4) + cl;                                  \
        bfr[nf] = *(const bf16x8*)((const char*)Bs + (((r << 7) + kof) ^ ((r & 7) << 4))); \
      }                                                                            \
      _Pragma("unroll")                                                            \
      for (int mf = 0; mf < 4; ++mf)                                               \
        _Pragma("unroll")                                                          \
        for (int nf = 0; nf < 4; ++nf)                                             \
          acc[mf][nf] = __builtin_amdgcn_mfma_f32_16x16x32_bf16(af[mf], bfr[nf], acc[mf][nf], 0, 0, 0); \
    }                                                                              \
  }

// ---------------------------------------------------------------------------
// Kernel 1: fused QKV projection. Grid (64, 24). blockIdx.y selects W and
// epilogue: y>>3 = 0 -> Q (RoPE), 1 -> K (RoPE), 2 -> V (transpose to VT).
// Outputs bf16: Q/K [bh][s][64], VT [bh][d][s].
// ---------------------------------------------------------------------------
__global__ __launch_bounds__(256) void gemm_qkv(
    const unsigned short* __restrict__ A,
    const unsigned short* __restrict__ Wqb, const unsigned short* __restrict__ Wkb,
    const unsigned short* __restrict__ Wvb,
    unsigned short* __restrict__ Qo, unsigned short* __restrict__ Ko,
    unsigned short* __restrict__ Vo,
    const float* __restrict__ cosT, const float* __restrict__ sinT) {
  __shared__ short As[128 * 64];
  __shared__ short Bs[128 * 64];
  const int t    = threadIdx.x;
  const int lane = t & 63;
  const int w    = t >> 6;
  const int wm   = w >> 1, wn = w & 1;
  const int cl   = lane & 15;
  const int rg   = lane >> 4;
  const int mBase = blockIdx.x << 7;
  const int nSel  = blockIdx.y >> 3;
  const int nBase = (blockIdx.y & 7) << 7;
  const unsigned short* W = (nSel == 0) ? Wqb : (nSel == 1) ? Wkb : Wvb;

  GEMM_CORE(A, W, mBase, nBase)

  if (nSel < 2) {
    // RoPE + bf16 scatter to [bh][s][64]
    unsigned short* out = (nSel == 0) ? Qo : Ko;
    const int h = (nBase >> 6) + wn;
#pragma unroll
    for (int nf = 0; nf < 4; ++nf) {
      const int d    = (nf << 4) + cl;
      const int pi   = d >> 1;
      const bool odd = d & 1;
#pragma unroll
      for (int mf = 0; mf < 4; ++mf) {
#pragma unroll
        for (int r = 0; r < 4; ++r) {
          const int m = mBase + (wm << 6) + (mf << 4) + (rg << 2) + r;
          const int s = m & (S_LEN - 1);
          const int b = m >> 11;
          float v = acc[mf][nf][r];
          const float other = __shfl_xor(v, 1);  // partner column d^1
          const float c  = cosT[(s << 5) + pi];
          const float sn = sinT[(s << 5) + pi];
          v = v * c + (odd ? other * sn : -other * sn);
          out[((size_t)(b * NHEAD + h) * S_LEN + s) * DHEAD + d] = (unsigned short)f2bf(v);
        }
      }
    }
  } else {
    // V: bf16 transposed scatter to VT [bh][d][s]
    typedef __attribute__((ext_vector_type(4))) short bf16x4;
    const int h = (nBase >> 6) + wn;
#pragma unroll
    for (int mf = 0; mf < 4; ++mf) {
      const int m0 = mBase + (wm << 6) + (mf << 4) + (rg << 2);
      const int s0 = m0 & (S_LEN - 1);
      const int b  = m0 >> 11;
#pragma unroll
      for (int nf = 0; nf < 4; ++nf) {
        const int d = (nf << 4) + cl;
        bf16x4 pk;
        pk[0] = f2bf(acc[mf][nf][0]); pk[1] = f2bf(acc[mf][nf][1]);
        pk[2] = f2bf(acc[mf][nf][2]); pk[3] = f2bf(acc[mf][nf][3]);
        *(bf16x4*)(Vo + ((size_t)(b * NHEAD + h) * DHEAD + d) * S_LEN + s0) = pk;
      }
    }
  }
}

// ---------------------------------------------------------------------------
// Kernel 3: out-projection. A bf16 (8192x1024), W bf16; fp32 out [m][n].
// ---------------------------------------------------------------------------
__global__ __launch_bounds__(256) void gemm_plain(
    const unsigned short* __restrict__ A, const unsigned short* __restrict__ W,
    float* __restrict__ out) {
  __shared__ short As[128 * 64];
  __shared__ short Bs[128 * 64];
  const int t    = threadIdx.x;
  const int lane = t & 63;
  const int w    = t >> 6;
  const int wm   = w >> 1, wn = w & 1;
  const int cl   = lane & 15;
  const int rg   = lane >> 4;
  const int mBase = blockIdx.x << 7;
  const int nBase = blockIdx.y << 7;

  GEMM_CORE(A, W, mBase, nBase)

#pragma unroll
  for (int mf = 0; mf < 4; ++mf) {
    const int rowb = mBase + (wm << 6) + (mf << 4) + (rg << 2);
#pragma unroll
    for (int nf = 0; nf < 4; ++nf) {
      const int col = nBase + (wn << 6) + (nf << 4) + cl;
#pragma unroll
      for (int r = 0; r < 4; ++r)
        out[(size_t)(rowb + r) * DMODEL + col] = acc[mf][nf][r];
    }
  }
}

// ---------------------------------------------------------------------------
// Kernel 2: causal flash attention, bf16 MFMA (structure HW-verified r5).
// Grid (16, 64); block (p,bh) does q-tiles {p, 31-p}. Output now bf16.
// ---------------------------------------------------------------------------
__global__ __launch_bounds__(256) void attn_mfma(const unsigned short* __restrict__ Qbf,
                                                 const unsigned short* __restrict__ Kbf,
                                                 const unsigned short* __restrict__ VTbf,
                                                 unsigned short* __restrict__ O) {
  __shared__ short Qs[64 * 64];
  __shared__ short Ks[64 * 64];
  __shared__ short Vs[64 * 64];
  __shared__ short Ps[64 * 64];
  const int t    = threadIdx.x;
  const int lane = t & 63;
  const int w    = t >> 6;
  const int cl   = lane & 15;
  const int rg   = lane >> 4;
  const int qw   = w << 4;
  const int bh   = blockIdx.y;
  const int p    = blockIdx.x;
  const int b    = bh >> 4, h = bh & 15;

  const unsigned short* kbase = Kbf + (size_t)bh * S_LEN * DHEAD;
  const unsigned short* vbase = VTbf + (size_t)bh * DHEAD * S_LEN;

  const int srow  = t >> 2;
  const int sslot = t & 3;

  for (int pass = 0; pass < 2; ++pass) {
    const int qt = pass ? (31 - p) : p;
    const int q0 = qt << 6;

    // stage Q (wave-private rows qw..qw+15)
    {
      const int qrow = qw + (lane >> 2);
      const int qsl  = lane & 3;
      const unsigned short* qp =
          Qbf + ((size_t)bh * S_LEN + q0 + qrow) * DHEAD + (qsl << 4);
      const bf16x8 qa = *(const bf16x8*)qp;
      const bf16x8 qb = *(const bf16x8*)(qp + 8);
      asm volatile("s_waitcnt lgkmcnt(0)" ::: "memory");
      *(bf16x8*)((char*)Qs + SW(qrow, (qsl << 5)))      = qa;
      *(bf16x8*)((char*)Qs + SW(qrow, (qsl << 5) + 16)) = qb;
    }

    f32x4 oacc[4];
#pragma unroll
    for (int nf = 0; nf < 4; ++nf) oacc[nf] = (f32x4){0.f, 0.f, 0.f, 0.f};
    float m_run[4], l_run[4];
#pragma unroll
    for (int r = 0; r < 4; ++r) { m_run[r] = -3.0e38f; l_run[r] = 0.0f; }

    for (int tk = 0; tk <= qt; ++tk) {
      const int kv0 = tk << 6;
      const unsigned short* kp = kbase + (size_t)(kv0 + srow) * DHEAD + (sslot << 4);
      const unsigned short* vp = vbase + (size_t)srow * S_LEN + kv0 + (sslot << 4);
      const bf16x8 k0 = *(const bf16x8*)kp;
      const bf16x8 k1 = *(const bf16x8*)(kp + 8);
      const bf16x8 v0 = *(const bf16x8*)vp;
      const bf16x8 v1 = *(const bf16x8*)(vp + 8);
      __syncthreads();  // A: previous tile's LDS reads complete
      *(bf16x8*)((char*)Ks + SW(srow, (sslot << 5)))      = k0;
      *(bf16x8*)((char*)Ks + SW(srow, (sslot << 5) + 16)) = k1;
      *(bf16x8*)((char*)Vs + SW(srow, (sslot << 5)))      = v0;
      *(bf16x8*)((char*)Vs + SW(srow, (sslot << 5) + 16)) = v1;
      __syncthreads();  // B: tiles ready

      // QK^T
      f32x4 sfrag[4];
#pragma unroll
      for (int nf = 0; nf < 4; ++nf) sfrag[nf] = (f32x4){0.f, 0.f, 0.f, 0.f};
#pragma unroll
      for (int ks = 0; ks < 2; ++ks) {
        const bf16x8 aq = *(const bf16x8*)((const char*)Qs + SW(qw + cl, (ks << 6) + (rg << 4)));
#pragma unroll
        for (int nf = 0; nf < 4; ++nf) {
          const bf16x8 bk = *(const bf16x8*)((const char*)Ks + SW((nf << 4) + cl, (ks << 6) + (rg << 4)));
          sfrag[nf] = __builtin_amdgcn_mfma_f32_16x16x32_bf16(aq, bk, sfrag[nf], 0, 0, 0);
        }
      }

      // online softmax
      const bool diag = (tk == qt);
      float esc4[4];
#pragma unroll
      for (int r = 0; r < 4; ++r) {
        const int qg = q0 + qw + (rg << 2) + r;
        float sv[4];
#pragma unroll
        for (int nf = 0; nf < 4; ++nf) {
          float x = sfrag[nf][r] * 0.125f;
          if (diag && (kv0 + (nf << 4) + cl > qg)) x = -1.0e9f;
          sv[nf] = x;
        }
        float tm = fmaxf(fmaxf(sv[0], sv[1]), fmaxf(sv[2], sv[3]));
        tm = fmaxf(tm, __shfl_xor(tm, 1));
        tm = fmaxf(tm, __shfl_xor(tm, 2));
        tm = fmaxf(tm, __shfl_xor(tm, 4));
        tm = fmaxf(tm, __shfl_xor(tm, 8));
        const float mn  = fmaxf(m_run[r], tm);
        const float esc = __expf(m_run[r] - mn);
        m_run[r] = mn;
        float rs = 0.0f;
        unsigned short pb[4];
#pragma unroll
        for (int nf = 0; nf < 4; ++nf) {
          const float pv = __expf(sv[nf] - mn);
          rs += pv;
          pb[nf] = (unsigned short)f2bf(pv);
        }
        rs += __shfl_xor(rs, 1);
        rs += __shfl_xor(rs, 2);
        rs += __shfl_xor(rs, 4);
        rs += __shfl_xor(rs, 8);
        l_run[r] = l_run[r] * esc + rs;
        esc4[r] = esc;
        const int prow = qw + (rg << 2) + r;
#pragma unroll
        for (int nf = 0; nf < 4; ++nf)
          *(unsigned short*)((char*)Ps + SW(prow, (nf << 5) + (cl << 1))) = pb[nf];
      }

#pragma unroll
      for (int nf = 0; nf < 4; ++nf)
#pragma unroll
        for (int r = 0; r < 4; ++r) oacc[nf][r] *= esc4[r];

      asm volatile("s_waitcnt lgkmcnt(0)" ::: "memory");  // P visible (same wave)

      // PV
#pragma unroll
      for (int ks = 0; ks < 2; ++ks) {
        const bf16x8 ap = *(const bf16x8*)((const char*)Ps + SW(qw + cl, (ks << 6) + (rg << 4)));
#pragma unroll
        for (int nf = 0; nf < 4; ++nf) {
          const bf16x8 bv = *(const bf16x8*)((const char*)Vs + SW((nf << 4) + cl, (ks << 6) + (rg << 4)));
          oacc[nf] = __builtin_amdgcn_mfma_f32_16x16x32_bf16(ap, bv, oacc[nf], 0, 0, 0);
        }
      }
    }

    // epilogue: normalize, write bf16 (B,S,H*dh)
#pragma unroll
    for (int r = 0; r < 4; ++r) {
      const float inv = 1.0f / l_run[r];
      const int sg = q0 + qw + (rg << 2) + r;
      unsigned short* orow = O + ((size_t)b * S_LEN + sg) * DMODEL + h * DHEAD;
#pragma unroll
      for (int nf = 0; nf < 4; ++nf)
        orow[(nf << 4) + cl] = (unsigned short)f2bf(oacc[nf][r] * inv);
    }
  }
}

// ---------------------------------------------------------------------------
extern "C" void kernel_launch(void* const* d_in, const int* in_sizes, int n_in,
                              void* d_out, int out_size, void* d_ws, size_t ws_size,
                              hipStream_t stream) {
  const float* x  = (const float*)d_in[0];
  const float* Wq = (const float*)d_in[1];
  const float* Wk = (const float*)d_in[2];
  const float* Wv = (const float*)d_in[3];
  const float* Wo = (const float*)d_in[4];
  // num_heads (d_in[5]) hardcoded as 16

  // workspace (all bf16 except tables):
  // xbf 16.8MB | Wq/Wk/Wv/Wo bf 2MB each | Qbf/Kbf/VTbf 16.8 each | Awbf 16.8 | tables 0.5
  unsigned short* xbf  = (unsigned short*)d_ws;
  unsigned short* Wqb  = xbf + (size_t)8388608;
  unsigned short* Wkb  = Wqb + (size_t)1048576;
  unsigned short* Wvb  = Wkb + (size_t)1048576;
  unsigned short* Wob  = Wvb + (size_t)1048576;
  unsigned short* Qbf  = Wob + (size_t)1048576;
  unsigned short* Kbf  = Qbf + (size_t)8388608;
  unsigned short* VTbf = Kbf + (size_t)8388608;
  unsigned short* Awbf = VTbf + (size_t)8388608;
  float* cosT = (float*)(Awbf + (size_t)8388608);
  float* sinT = cosT + 65536;  // total ~83.9 MB

  rope_table_kernel<<<256, 256, 0, stream>>>(cosT, sinT);
  convert_kernel<<<6144, 256, 0, stream>>>(x, Wq, Wk, Wv, Wo, xbf, Wqb, Wkb, Wvb, Wob);

  gemm_qkv<<<dim3(64, 24), 256, 0, stream>>>(xbf, Wqb, Wkb, Wvb, Qbf, Kbf, VTbf, cosT, sinT);

  attn_mfma<<<dim3(16, 64), 256, 0, stream>>>(Qbf, Kbf, VTbf, Awbf);

  gemm_plain<<<dim3(64, 8), 256, 0, stream>>>(Awbf, Wob, (float*)d_out);
}